// Round 3
// baseline (5132.309 us; speedup 1.0000x reference)
//
#include <hip/hip_runtime.h>
#include <hip/hip_bf16.h>

#define SLEN 128
#define BAT 64
#define EDIM 512
#define HDIM 1024
#define VOC 10000
#define VPAD 10112     // 79 * 128
#define NWG_REC 192
#define TPB_REC 512

typedef short v8s __attribute__((ext_vector_type(8)));
typedef float v4f __attribute__((ext_vector_type(4)));
typedef unsigned short u16;

__device__ __forceinline__ u16 f2bf(float f) {
  unsigned u = __float_as_uint(f);
  u += 0x7fffu + ((u >> 16) & 1u);   // RNE
  return (u16)(u >> 16);
}
__device__ __forceinline__ float bf2f(u16 b) {
  return __uint_as_float(((unsigned)b) << 16);
}
__device__ __forceinline__ float sigm(float x) { return 1.f / (1.f + __expf(-x)); }
__device__ __forceinline__ float tanh_f(float x) { return 1.f - 2.f / (1.f + __expf(2.f * x)); }

// ---------------- RMW-free grid barrier ------------------------------------------
// Each WG release-stores flags[wg]=ph (192 parallel stores, no atomic RMW chain).
// Wave 0 of every WG polls all 192 flags via 3 coalesced per-lane agent loads.
// ph is monotonically increasing across the whole kernel -> no reset, ">=" compare.
__device__ __forceinline__ void gbar(int* flags, int ph, int wg, int t) {
  __syncthreads();
  if (t == 0)
    __hip_atomic_store(&flags[wg], ph, __ATOMIC_RELEASE, __HIP_MEMORY_SCOPE_AGENT);
  if (t < 64) {
    bool ok;
    do {
      int v0 = __hip_atomic_load(&flags[t],       __ATOMIC_RELAXED, __HIP_MEMORY_SCOPE_AGENT);
      int v1 = __hip_atomic_load(&flags[64 + t],  __ATOMIC_RELAXED, __HIP_MEMORY_SCOPE_AGENT);
      int v2 = __hip_atomic_load(&flags[128 + t], __ATOMIC_RELAXED, __HIP_MEMORY_SCOPE_AGENT);
      ok = (v0 >= ph) & (v1 >= ph) & (v2 >= ph);
    } while (!__all(ok));
    __builtin_amdgcn_fence(__ATOMIC_ACQUIRE, "agent");
  }
  __syncthreads();
}

// One 16x16x1024 GEMM tile: A (16 rows from batch-major global), B from swizzled LDS.
// Lane l: lr=l&15 is both A-row and B-col index; lk=(l>>4)*8 is k element offset.
__device__ __forceinline__ v4f gemm16(const u16* __restrict__ A,
                                      const char* __restrict__ Blds,
                                      int rg, int cg, int lr, int lk) {
  const u16* ap = A + (rg * 16 + lr) * HDIM + lk;
  const int c = cg * 16 + lr;              // local weight column 0..31
  const int swz = (c & 7) << 4;
  const char* bbase = Blds + c * 2048;
  const int lk2 = lk * 2;
  v4f acc{0.f, 0.f, 0.f, 0.f};
#pragma unroll 8
  for (int ks = 0; ks < 32; ++ks) {
    v8s a = *(const v8s*)(ap + ks * 32);
    v8s b = *(const v8s*)(bbase + ((ks * 64 + lk2) ^ swz));
    acc = __builtin_amdgcn_mfma_f32_16x16x32_bf16(a, b, acc, 0, 0, 0);
  }
  return acc;
}

// ---------------- persistent 2-layer GRU recurrence -------------------------------
// Weights persist in LDS (96KB/WG, swizzled), loaded once before the T-loop.
// Per tick T (2 barriers):
//  P1 (8 waves: rg=w>>1, cg=w&1, 32 cols/WG):
//    rz0(T)    wg 0..63   A=h0b B=Uh0[rz]  -> a2,z0
//    xp1(T-1)  wg 64..159 A=h0b B=Wx1      -> xp1 buffer (bf16)
//    ht1(T-2)  wg 160..191 A=a5 B=Uh1[h]   -> h1 update + hs1
//  P2 (waves 0..3, 16 cols/WG):
//    ht0(T)    wg 0..63   A=a2 B=Uh0[h]    -> h0 update
//    rz1(T-1)  wg 64..191 A=h1b B=Uh1[rz]  -> a5,z1
__global__ void __launch_bounds__(512, 2) k_recur(
    const u16* __restrict__ Uh0b, const u16* __restrict__ Wx1b, const u16* __restrict__ Uh1b,
    const float* __restrict__ b0, const float* __restrict__ b1,
    const u16* __restrict__ xa0,
    float* __restrict__ h0f, u16* __restrict__ h0b,
    float* __restrict__ h1f, u16* __restrict__ h1b,
    u16* __restrict__ a2, float* __restrict__ z0,
    u16* __restrict__ a5, float* __restrict__ z1,
    u16* __restrict__ xp1,
    u16* __restrict__ hs1,
    float* __restrict__ outh,
    int* __restrict__ bar) {
  extern __shared__ char smem[];     // [0,64K): P1 weights (32 cols); [64K,96K): P2 (16 cols)
  const int wg = blockIdx.x;
  const int t = threadIdx.x;
  const int w = t >> 6;
  const int l = t & 63;
  const int lr = l & 15;
  const int lk = (l >> 4) * 8;
  const int rg = w >> 1, cg = w & 1;
  const int rbase1 = rg * 16 + ((l >> 4) << 2);
  const int rbase2 = w * 16 + ((l >> 4) << 2);

  // ---- one-time weight staging into swizzled LDS ----
  {
    const u16* w1src; int w1row0;
    if (wg < 64)       { w1src = Uh0b; w1row0 = wg * 32; }
    else if (wg < 160) { w1src = Wx1b; w1row0 = (wg - 64) * 32; }
    else               { w1src = Uh1b; w1row0 = 2048 + (wg - 160) * 32; }
    const u16* w2src; int w2row0;
    if (wg < 64) { w2src = Uh0b; w2row0 = 2048 + wg * 16; }
    else         { w2src = Uh1b; w2row0 = (wg - 64) * 16; }
    for (int i = t; i < 4096; i += TPB_REC) {          // 32 cols * 128 x 16B
      int c = i >> 7, j = i & 127;
      v8s v = *(const v8s*)(w1src + (size_t)(w1row0 + c) * HDIM + j * 8);
      int off = c * 2048 + ((j * 16) ^ ((c & 7) << 4));
      *(v8s*)(smem + off) = v;
    }
    for (int i = t; i < 2048; i += TPB_REC) {          // 16 cols * 128 x 16B
      int c = i >> 7, j = i & 127;
      v8s v = *(const v8s*)(w2src + (size_t)(w2row0 + c) * HDIM + j * 8);
      int off = 65536 + c * 2048 + ((j * 16) ^ ((c & 7) << 4));
      *(v8s*)(smem + off) = v;
    }
    __syncthreads();
  }

  for (int T = 0; T <= SLEN + 1; ++T) {
    // ---------------- Phase 1 ----------------
    if (wg < 64) {
      if (T < SLEN) {
        v4f acc = gemm16(h0b, smem, rg, cg, lr, lk);
        const int cglob = wg * 32 + cg * 16 + lr;      // 0..2047
        const int g = cglob >> 10;                     // uniform per WG
        const int o = cglob & 1023;
        const float bias = b0[g * HDIM + o];
#pragma unroll
        for (int r = 0; r < 4; ++r) {
          int b = rbase1 + r;
          float x = acc[r] + bf2f(xa0[((T * 3 + g) * BAT + b) * HDIM + o]) + bias;
          float s = sigm(x);
          if (g == 0) a2[b * HDIM + o] = f2bf(s * h0f[b * HDIM + o]);
          else        z0[b * HDIM + o] = s;
        }
      }
    } else if (wg < 160) {
      if (T >= 1 && T <= SLEN) {
        v4f acc = gemm16(h0b, smem, rg, cg, lr, lk);
        const int n = (wg - 64) * 32 + cg * 16 + lr;   // 0..3071
        u16* xp = xp1 + ((T - 1) & 1) * (BAT * 3 * HDIM);
#pragma unroll
        for (int r = 0; r < 4; ++r) xp[(rbase1 + r) * 3072 + n] = f2bf(acc[r]);
      }
    } else {
      if (T >= 2) {
        const int t5 = T - 2;
        v4f acc = gemm16(a5, smem, rg, cg, lr, lk);
        const int o = (wg - 160) * 32 + cg * 16 + lr;  // 0..1023
        const u16* xp = xp1 + (t5 & 1) * (BAT * 3 * HDIM);
        const float bias = b1[2 * HDIM + o];
#pragma unroll
        for (int r = 0; r < 4; ++r) {
          int b = rbase1 + r;
          float ht = tanh_f(bf2f(xp[b * 3072 + 2048 + o]) + acc[r] + bias);
          float z = z1[b * HDIM + o];
          float hn = (1.f - z) * h1f[b * HDIM + o] + z * ht;
          h1f[b * HDIM + o] = hn;
          u16 hb = f2bf(hn);
          h1b[b * HDIM + o] = hb;
          hs1[((size_t)t5 * BAT + b) * HDIM + o] = hb;
          if (t5 == SLEN - 1) outh[(size_t)BAT * HDIM + b * HDIM + o] = hn;
        }
      }
    }
    gbar(bar, 2 * T + 1, wg, t);
    // ---------------- Phase 2 (waves 0..3 only) ----------------
    if (w < 4) {
      if (wg < 64) {
        if (T < SLEN) {
          v4f acc = gemm16(a2, smem + 65536, w, 0, lr, lk);
          const int o = wg * 16 + lr;                  // 0..1023
          const float bias = b0[2 * HDIM + o];
#pragma unroll
          for (int r = 0; r < 4; ++r) {
            int b = rbase2 + r;
            float ht = tanh_f(bf2f(xa0[((T * 3 + 2) * BAT + b) * HDIM + o]) + acc[r] + bias);
            float z = z0[b * HDIM + o];
            float hn = (1.f - z) * h0f[b * HDIM + o] + z * ht;
            h0f[b * HDIM + o] = hn;
            h0b[b * HDIM + o] = f2bf(hn);
            if (T == SLEN - 1) outh[b * HDIM + o] = hn;
          }
        }
      } else {
        if (T >= 1 && T <= SLEN) {
          const int t4 = T - 1;
          v4f acc = gemm16(h1b, smem + 65536, w, 0, lr, lk);
          const int cglob = (wg - 64) * 16 + lr;       // 0..2047
          const int g = cglob >> 10;                   // uniform per WG
          const int o = cglob & 1023;
          const u16* xp = xp1 + (t4 & 1) * (BAT * 3 * HDIM);
          const float bias = b1[g * HDIM + o];
#pragma unroll
          for (int r = 0; r < 4; ++r) {
            int b = rbase2 + r;
            float x = acc[r] + bf2f(xp[b * 3072 + g * HDIM + o]) + bias;
            float s = sigm(x);
            if (g == 0) a5[b * HDIM + o] = f2bf(s * h1f[b * HDIM + o]);
            else        z1[b * HDIM + o] = s;
          }
        }
      }
    }
    gbar(bar, 2 * T + 2, wg, t);
  }
}

// ---------------- m97-style 128x128 bf16 GEMM ------------------------------------
// MODE 0: xa0 = gather(emb)[8192,512] x Wx0[3072,512]^T -> bf16 out in (S,3,B,H) layout
// MODE 1: logits = hs1[8192,1024] x Wd[VPAD,1024]^T + bd -> f32 (8192,10000)
template <int MODE>
__global__ void __launch_bounds__(256) k_gemm(
    const u16* __restrict__ A, const u16* __restrict__ Bw,
    const int* __restrict__ gidx, const float* __restrict__ bias,
    void* __restrict__ Out) {
  constexpr int K = MODE ? 1024 : 512;
  constexpr int NB_N = MODE ? (VPAD / 128) : (3072 / 128);

  __shared__ u16 sA[128 * 64];
  __shared__ u16 sB[128 * 64];

  const int nwg = gridDim.x;
  const int cpx = nwg >> 3;               // nwg % 8 == 0 for both grids
  const int bid = blockIdx.x;
  const int swz = (bid & 7) * cpx + (bid >> 3);
  const int bm = swz / NB_N, bn = swz % NB_N;
  const int m0 = bm * 128, n0 = bn * 128;

  const int t = threadIdx.x;
  const int w = t >> 6, l = t & 63;
  const int lr = l & 15, lk = (l >> 4) * 8;
  const int wm = (w >> 1) * 64, wn = (w & 1) * 64;
  const int kc = (t & 7) * 8;

  int arowg[4];
#pragma unroll
  for (int i = 0; i < 4; ++i) {
    int row = m0 + i * 32 + (t >> 3);
    arowg[i] = (MODE == 0) ? gidx[row] : row;
  }
  int brow[4];
#pragma unroll
  for (int i = 0; i < 4; ++i) brow[i] = n0 + i * 32 + (t >> 3);

  v4f acc[4][4];
#pragma unroll
  for (int mi = 0; mi < 4; ++mi)
#pragma unroll
    for (int ni = 0; ni < 4; ++ni) acc[mi][ni] = v4f{0.f, 0.f, 0.f, 0.f};

  for (int k0 = 0; k0 < K; k0 += 64) {
    __syncthreads();
#pragma unroll
    for (int i = 0; i < 4; ++i) {
      const u16* src = A + (size_t)arowg[i] * K + k0 + kc;
      __builtin_amdgcn_global_load_lds((const __attribute__((address_space(1))) void*)src,
                                       (__attribute__((address_space(3))) void*)(sA + i * 2048 + w * 512),
                                       16, 0, 0);
    }
#pragma unroll
    for (int i = 0; i < 4; ++i) {
      const u16* src = Bw + (size_t)brow[i] * K + k0 + kc;
      __builtin_amdgcn_global_load_lds((const __attribute__((address_space(1))) void*)src,
                                       (__attribute__((address_space(3))) void*)(sB + i * 2048 + w * 512),
                                       16, 0, 0);
    }
    asm volatile("s_waitcnt vmcnt(0)" ::: "memory");
    __syncthreads();
#pragma unroll
    for (int ks = 0; ks < 2; ++ks) {
      v8s af[4], bfr[4];
#pragma unroll
      for (int mi = 0; mi < 4; ++mi) af[mi] = *(const v8s*)&sA[(wm + mi * 16 + lr) * 64 + ks * 32 + lk];
#pragma unroll
      for (int ni = 0; ni < 4; ++ni) bfr[ni] = *(const v8s*)&sB[(wn + ni * 16 + lr) * 64 + ks * 32 + lk];
#pragma unroll
      for (int mi = 0; mi < 4; ++mi)
#pragma unroll
        for (int ni = 0; ni < 4; ++ni)
          acc[mi][ni] = __builtin_amdgcn_mfma_f32_16x16x32_bf16(af[mi], bfr[ni], acc[mi][ni], 0, 0, 0);
    }
  }

#pragma unroll
  for (int mi = 0; mi < 4; ++mi)
#pragma unroll
    for (int ni = 0; ni < 4; ++ni)
#pragma unroll
      for (int r = 0; r < 4; ++r) {
        int grow = m0 + wm + mi * 16 + ((l >> 4) << 2) + r;
        int gcol = n0 + wn + ni * 16 + lr;
        float v = acc[mi][ni][r];
        if (MODE == 0) {
          int s = grow >> 6, b = grow & 63;
          int g = gcol >> 10, o = gcol & 1023;
          ((u16*)Out)[(((size_t)s * 3 + g) * BAT + b) * HDIM + o] = f2bf(v);
        } else {
          if (gcol < VOC) ((float*)Out)[(size_t)grow * VOC + gcol] = v + bias[gcol];
        }
      }
}

// ---------------- small helper kernels --------------------------------------------
__global__ void k_cvt(const float* __restrict__ src, u16* __restrict__ dst, int n, int nsrc) {
  int i = (blockIdx.x * 256 + threadIdx.x) * 4;
  if (i >= n) return;
#pragma unroll
  for (int j = 0; j < 4; ++j) {
    int idx = i + j;
    if (idx < n) dst[idx] = (idx < nsrc) ? f2bf(src[idx]) : (u16)0;
  }
}

__global__ void k_init(const float* __restrict__ hidden,
                       float* h0f, u16* h0b, float* h1f, u16* h1b, int* bar) {
  int i = blockIdx.x * 256 + threadIdx.x;
  if (i < BAT * HDIM) {
    float v0 = hidden[i];
    float v1 = hidden[BAT * HDIM + i];
    h0f[i] = v0; h0b[i] = f2bf(v0);
    h1f[i] = v1; h1b[i] = f2bf(v1);
  }
  if (i < 512) bar[i] = 0;
}

// ---------------- launcher ---------------------------------------------------------
extern "C" void kernel_launch(void* const* d_in, const int* in_sizes, int n_in,
                              void* d_out, int out_size, void* d_ws, size_t ws_size,
                              hipStream_t stream) {
  const int*   inp = (const int*)d_in[0];
  const float* hid = (const float*)d_in[1];
  const float* emb = (const float*)d_in[2];
  const float* Wx0 = (const float*)d_in[3];
  const float* Uh0 = (const float*)d_in[4];
  const float* b0  = (const float*)d_in[5];
  const float* Wx1 = (const float*)d_in[6];
  const float* Uh1 = (const float*)d_in[7];
  const float* b1  = (const float*)d_in[8];
  const float* Wd  = (const float*)d_in[9];
  const float* bd  = (const float*)d_in[10];

  char* ws = (char*)d_ws;
  size_t off = 0;
  auto alloc = [&](size_t bytes) {
    void* p = ws + off;
    off = (off + bytes + 255) & ~(size_t)255;
    return p;
  };
  u16* emb_b = (u16*)alloc(sizeof(u16) * (size_t)VOC * EDIM);
  u16* Wx0_b = (u16*)alloc(sizeof(u16) * 3 * HDIM * EDIM);
  u16* Uh0_b = (u16*)alloc(sizeof(u16) * 3 * HDIM * HDIM);
  u16* Wx1_b = (u16*)alloc(sizeof(u16) * 3 * HDIM * HDIM);
  u16* Uh1_b = (u16*)alloc(sizeof(u16) * 3 * HDIM * HDIM);
  u16* Wd_b  = (u16*)alloc(sizeof(u16) * (size_t)VPAD * HDIM);
  u16* xa0_b = (u16*)alloc(sizeof(u16) * (size_t)SLEN * 3 * BAT * HDIM);
  u16* hs1_b = (u16*)alloc(sizeof(u16) * (size_t)SLEN * BAT * HDIM);
  u16* xp1   = (u16*)alloc(sizeof(u16) * 2 * BAT * 3 * HDIM);
  float* h0f = (float*)alloc(sizeof(float) * BAT * HDIM);
  float* h1f = (float*)alloc(sizeof(float) * BAT * HDIM);
  u16* h0b   = (u16*)alloc(sizeof(u16) * BAT * HDIM);
  u16* h1b   = (u16*)alloc(sizeof(u16) * BAT * HDIM);
  u16* a2    = (u16*)alloc(sizeof(u16) * BAT * HDIM);
  u16* a5    = (u16*)alloc(sizeof(u16) * BAT * HDIM);
  float* z0  = (float*)alloc(sizeof(float) * BAT * HDIM);
  float* z1  = (float*)alloc(sizeof(float) * BAT * HDIM);
  int* bar   = (int*)alloc(sizeof(int) * 512);

  float* logits = (float*)d_out;
  float* outh = logits + (size_t)SLEN * BAT * VOC;

  auto cvt = [&](const float* s, u16* d, int n, int nsrc) {
    k_cvt<<<dim3((n / 4 + 255) / 256), dim3(256), 0, stream>>>(s, d, n, nsrc);
  };
  cvt(emb, emb_b, VOC * EDIM, VOC * EDIM);
  cvt(Wx0, Wx0_b, 3 * HDIM * EDIM, 3 * HDIM * EDIM);
  cvt(Uh0, Uh0_b, 3 * HDIM * HDIM, 3 * HDIM * HDIM);
  cvt(Wx1, Wx1_b, 3 * HDIM * HDIM, 3 * HDIM * HDIM);
  cvt(Uh1, Uh1_b, 3 * HDIM * HDIM, 3 * HDIM * HDIM);
  cvt(Wd, Wd_b, VPAD * HDIM, VOC * HDIM);
  k_init<<<dim3(256), dim3(256), 0, stream>>>(hid, h0f, h0b, h1f, h1b, bar);

  k_gemm<0><<<dim3(64 * 24), dim3(256), 0, stream>>>(emb_b, Wx0_b, inp, (const float*)nullptr, (void*)xa0_b);

  (void)hipFuncSetAttribute(reinterpret_cast<const void*>(k_recur),
                            hipFuncAttributeMaxDynamicSharedMemorySize, 96 * 1024);
  k_recur<<<dim3(NWG_REC), dim3(TPB_REC), 96 * 1024, stream>>>(
      Uh0_b, Wx1_b, Uh1_b, b0, b1, xa0_b,
      h0f, h0b, h1f, h1b, a2, z0, a5, z1, xp1, hs1_b, outh, bar);

  k_gemm<1><<<dim3(64 * 79), dim3(256), 0, stream>>>(hs1_b, Wd_b, (const int*)nullptr, bd, d_out);
}

// Round 4
// 3015.255 us; speedup vs baseline: 1.7021x; 1.7021x over previous
//
#include <hip/hip_runtime.h>
#include <hip/hip_bf16.h>

#define SLEN 128
#define BAT 64
#define EDIM 512
#define HDIM 1024
#define VOC 10000
#define VPAD 10112     // 79 * 128
#define NWG_REC 192
#define TPB_REC 512

typedef short v8s __attribute__((ext_vector_type(8)));
typedef float v4f __attribute__((ext_vector_type(4)));
typedef unsigned short u16;

__device__ __forceinline__ u16 f2bf(float f) {
  unsigned u = __float_as_uint(f);
  u += 0x7fffu + ((u >> 16) & 1u);   // RNE
  return (u16)(u >> 16);
}
__device__ __forceinline__ float bf2f(u16 b) {
  return __uint_as_float(((unsigned)b) << 16);
}
__device__ __forceinline__ float sigm(float x) { return 1.f / (1.f + __expf(-x)); }
__device__ __forceinline__ float tanh_f(float x) { return 1.f - 2.f / (1.f + __expf(2.f * x)); }

// ---- LLC-point scalar state accessors (relaxed agent atomics, no fences) ---------
__device__ __forceinline__ void st_f32(float* p, float v) {
  __hip_atomic_store(p, v, __ATOMIC_RELAXED, __HIP_MEMORY_SCOPE_AGENT);
}
__device__ __forceinline__ float ld_f32(const float* p) {
  return __hip_atomic_load(p, __ATOMIC_RELAXED, __HIP_MEMORY_SCOPE_AGENT);
}
// bf16 state element load from u32-aliased packed buffer
__device__ __forceinline__ float ld_bf16(const unsigned* base, int elem) {
  unsigned pr = __hip_atomic_load(base + (elem >> 1), __ATOMIC_RELAXED, __HIP_MEMORY_SCOPE_AGENT);
  return bf2f((u16)((elem & 1) ? (pr >> 16) : (pr & 0xffffu)));
}
// bf16 pair store: lanes l (even) and l^1 hold adjacent elements; even lane stores u32
__device__ __forceinline__ void st_bf16_pair(unsigned* base, int elem, u16 val, int l) {
  unsigned p = (unsigned)__shfl_xor((int)val, 1);
  if ((l & 1) == 0)
    __hip_atomic_store(base + (elem >> 1), (unsigned)val | (p << 16),
                       __ATOMIC_RELAXED, __HIP_MEMORY_SCOPE_AGENT);
}

// ---------------- fence-free two-level grid barrier -------------------------------
// All state moves via LLC-point atomics, so no cache maintenance is needed:
// per-wave s_waitcnt vmcnt(0) -> s_barrier -> flag store -> master aggregates ->
// workers poll one broadcast generation line with sleep backoff.
__device__ __forceinline__ void gbar(int* bar, int ph, int wg, int t) {
  asm volatile("s_waitcnt vmcnt(0) lgkmcnt(0)" ::: "memory");
  __syncthreads();
  if (t == 0)
    __hip_atomic_store(&bar[wg], ph, __ATOMIC_RELAXED, __HIP_MEMORY_SCOPE_AGENT);
  if (wg == 0) {
    if (t < 64) {
      for (;;) {
        int v0 = __hip_atomic_load(&bar[t],       __ATOMIC_RELAXED, __HIP_MEMORY_SCOPE_AGENT);
        int v1 = __hip_atomic_load(&bar[64 + t],  __ATOMIC_RELAXED, __HIP_MEMORY_SCOPE_AGENT);
        int v2 = __hip_atomic_load(&bar[128 + t], __ATOMIC_RELAXED, __HIP_MEMORY_SCOPE_AGENT);
        if (__all((v0 >= ph) & (v1 >= ph) & (v2 >= ph))) break;
        __builtin_amdgcn_s_sleep(1);
      }
      if (t == 0)
        __hip_atomic_store(&bar[256], ph, __ATOMIC_RELAXED, __HIP_MEMORY_SCOPE_AGENT);
    }
  } else if (t < 64) {
    while (__hip_atomic_load(&bar[256], __ATOMIC_RELAXED, __HIP_MEMORY_SCOPE_AGENT) < ph)
      __builtin_amdgcn_s_sleep(4);
  }
  __syncthreads();
}

// ---- 16x16xK GEMM tile: A via asm sc0/sc1 LLC loads (depth-8 pipeline), B from LDS
// apl: per-lane A base = A + (rowblk+lr)*2048 + (l>>4)*16 ; per ks step +64B.
// bcl: per-lane LDS col base; read (ks*64 + lk2) ^ swz.
__device__ __forceinline__ v4f gemm_sc(const char* apl, const char* bcl, int swz, int lk2) {
  v8s a[8];
  v4f acc0{0.f, 0.f, 0.f, 0.f}, acc1{0.f, 0.f, 0.f, 0.f};
#pragma unroll
  for (int j = 0; j < 8; ++j)
    asm volatile("global_load_dwordx4 %0, %1, off offset:%2 sc0 sc1"
                 : "=v"(a[j]) : "v"(apl), "i"(j * 64));
#pragma unroll
  for (int ks = 0; ks < 32; ++ks) {
    asm volatile("s_waitcnt vmcnt(%0)" :: "i"((ks < 24) ? 7 : (31 - ks)));
    __builtin_amdgcn_sched_barrier(0x3F6);   // everything but MFMA may cross
    v8s b = *(const v8s*)(bcl + ((ks * 64 + lk2) ^ swz));
    if (ks & 1) acc1 = __builtin_amdgcn_mfma_f32_16x16x32_bf16(a[ks & 7], b, acc1, 0, 0, 0);
    else        acc0 = __builtin_amdgcn_mfma_f32_16x16x32_bf16(a[ks & 7], b, acc0, 0, 0, 0);
    if (ks < 24)
      asm volatile("global_load_dwordx4 %0, %1, off offset:%2 sc0 sc1"
                   : "=v"(a[ks & 7]) : "v"(apl), "i"((ks + 8) * 64));
  }
  return acc0 + acc1;
}

// ---------------- persistent 2-layer GRU recurrence -------------------------------
// Weights persist in LDS (96KB/WG, swizzled). State: LLC-point atomics, no fences.
__global__ void __launch_bounds__(512, 2) k_recur(
    const u16* __restrict__ Uh0b, const u16* __restrict__ Wx1b, const u16* __restrict__ Uh1b,
    const float* __restrict__ b0, const float* __restrict__ b1,
    const u16* __restrict__ xa0,
    float* __restrict__ h0f, u16* __restrict__ h0b,
    float* __restrict__ h1f, u16* __restrict__ h1b,
    u16* __restrict__ a2, float* __restrict__ z0,
    u16* __restrict__ a5, float* __restrict__ z1,
    u16* __restrict__ xp1,
    u16* __restrict__ hs1,
    float* __restrict__ outh,
    int* __restrict__ bar) {
  extern __shared__ char smem[];     // [0,64K): P1 weights (32 cols); [64K,96K): P2 (16 cols)
  const int wg = blockIdx.x;
  const int t = threadIdx.x;
  const int w = t >> 6;
  const int l = t & 63;
  const int lr = l & 15;
  const int lk2 = (l >> 4) * 16;     // byte offset of k-chunk
  const int rg = w >> 1, cg = w & 1;
  const int rbase1 = rg * 16 + ((l >> 4) << 2);
  const int rbase2 = w * 16 + ((l >> 4) << 2);

  unsigned* a2u  = (unsigned*)a2;
  unsigned* a5u  = (unsigned*)a5;
  unsigned* h0bu = (unsigned*)h0b;
  unsigned* h1bu = (unsigned*)h1b;
  unsigned* xpu  = (unsigned*)xp1;

  // ---- one-time weight staging into swizzled LDS (read-only, normal loads) ----
  {
    const u16* w1src; int w1row0;
    if (wg < 64)       { w1src = Uh0b; w1row0 = wg * 32; }
    else if (wg < 160) { w1src = Wx1b; w1row0 = (wg - 64) * 32; }
    else               { w1src = Uh1b; w1row0 = 2048 + (wg - 160) * 32; }
    const u16* w2src; int w2row0;
    if (wg < 64) { w2src = Uh0b; w2row0 = 2048 + wg * 16; }
    else         { w2src = Uh1b; w2row0 = (wg - 64) * 16; }
    for (int i = t; i < 4096; i += TPB_REC) {
      int c = i >> 7, j = i & 127;
      v8s v = *(const v8s*)(w1src + (size_t)(w1row0 + c) * HDIM + j * 8);
      int off = c * 2048 + ((j * 16) ^ ((c & 7) << 4));
      *(v8s*)(smem + off) = v;
    }
    for (int i = t; i < 2048; i += TPB_REC) {
      int c = i >> 7, j = i & 127;
      v8s v = *(const v8s*)(w2src + (size_t)(w2row0 + c) * HDIM + j * 8);
      int off = 65536 + c * 2048 + ((j * 16) ^ ((c & 7) << 4));
      *(v8s*)(smem + off) = v;
    }
    __syncthreads();
  }

  const char* bb1 = smem + (cg * 16 + lr) * 2048;
  const int swz1 = ((cg * 16 + lr) & 7) << 4;
  const char* bb2 = smem + 65536 + lr * 2048;
  const int swz2 = (lr & 7) << 4;

  for (int T = 0; T <= SLEN + 1; ++T) {
    // ---------------- Phase 1 ----------------
    if (wg < 64) {
      if (T < SLEN) {
        const int cglob = wg * 32 + cg * 16 + lr;      // 0..2047
        const int g = cglob >> 10;                     // uniform per WG
        const int o = cglob & 1023;
        const float bias = b0[g * HDIM + o];
        float xv[4], hv[4];
#pragma unroll
        for (int r = 0; r < 4; ++r) {
          int b = rbase1 + r;
          xv[r] = bf2f(xa0[((T * 3 + g) * BAT + b) * HDIM + o]);
          if (g == 0) hv[r] = ld_f32(&h0f[b * HDIM + o]);
        }
        const char* apl = (const char*)h0b + (rg * 16 + lr) * 2048 + lk2;
        v4f acc = gemm_sc(apl, bb1, swz1, lk2);
#pragma unroll
        for (int r = 0; r < 4; ++r) {
          int b = rbase1 + r;
          float s = sigm(acc[r] + xv[r] + bias);
          if (g == 0) st_bf16_pair(a2u, b * HDIM + o, f2bf(s * hv[r]), l);
          else        st_f32(&z0[b * HDIM + o], s);
        }
      }
    } else if (wg < 160) {
      if (T >= 1 && T <= SLEN) {
        const int n = (wg - 64) * 32 + cg * 16 + lr;   // 0..3071
        const char* apl = (const char*)h0b + (rg * 16 + lr) * 2048 + lk2;
        v4f acc = gemm_sc(apl, bb1, swz1, lk2);
        unsigned* xp = xpu + (((T - 1) & 1) * (BAT * 3 * HDIM) >> 1);
#pragma unroll
        for (int r = 0; r < 4; ++r)
          st_bf16_pair(xp, (rbase1 + r) * 3072 + n, f2bf(acc[r]), l);
      }
    } else {
      if (T >= 2) {
        const int t5 = T - 2;
        const int o = (wg - 160) * 32 + cg * 16 + lr;  // 0..1023
        const unsigned* xp = xpu + (((t5 & 1) * (BAT * 3 * HDIM)) >> 1);
        const float bias = b1[2 * HDIM + o];
        float xv[4], zv[4], hv[4];
#pragma unroll
        for (int r = 0; r < 4; ++r) {
          int b = rbase1 + r;
          xv[r] = ld_bf16(xp, b * 3072 + 2048 + o);
          zv[r] = ld_f32(&z1[b * HDIM + o]);
          hv[r] = ld_f32(&h1f[b * HDIM + o]);
        }
        const char* apl = (const char*)a5 + (rg * 16 + lr) * 2048 + lk2;
        v4f acc = gemm_sc(apl, bb1, swz1, lk2);
#pragma unroll
        for (int r = 0; r < 4; ++r) {
          int b = rbase1 + r;
          float ht = tanh_f(xv[r] + acc[r] + bias);
          float hn = (1.f - zv[r]) * hv[r] + zv[r] * ht;
          u16 hb = f2bf(hn);
          st_f32(&h1f[b * HDIM + o], hn);
          st_bf16_pair(h1bu, b * HDIM + o, hb, l);
          hs1[((size_t)t5 * BAT + b) * HDIM + o] = hb;           // normal store
          if (t5 == SLEN - 1) outh[(size_t)BAT * HDIM + b * HDIM + o] = hn;
        }
      }
    }
    gbar(bar, 2 * T + 1, wg, t);
    // ---------------- Phase 2 (waves 0..3 only) ----------------
    if (w < 4) {
      if (wg < 64) {
        if (T < SLEN) {
          const int o = wg * 16 + lr;                  // 0..1023
          const float bias = b0[2 * HDIM + o];
          float xv[4], zv[4], hv[4];
#pragma unroll
          for (int r = 0; r < 4; ++r) {
            int b = rbase2 + r;
            xv[r] = bf2f(xa0[((T * 3 + 2) * BAT + b) * HDIM + o]);
            zv[r] = ld_f32(&z0[b * HDIM + o]);
            hv[r] = ld_f32(&h0f[b * HDIM + o]);
          }
          const char* apl = (const char*)a2 + (w * 16 + lr) * 2048 + lk2;
          v4f acc = gemm_sc(apl, bb2, swz2, lk2);
#pragma unroll
          for (int r = 0; r < 4; ++r) {
            int b = rbase2 + r;
            float ht = tanh_f(xv[r] + acc[r] + bias);
            float hn = (1.f - zv[r]) * hv[r] + zv[r] * ht;
            st_f32(&h0f[b * HDIM + o], hn);
            st_bf16_pair(h0bu, b * HDIM + o, f2bf(hn), l);
            if (T == SLEN - 1) outh[b * HDIM + o] = hn;
          }
        }
      } else {
        if (T >= 1 && T <= SLEN) {
          const int t4 = T - 1;
          const int cglob = (wg - 64) * 16 + lr;       // 0..2047
          const int g = cglob >> 10;                   // uniform per WG
          const int o = cglob & 1023;
          const unsigned* xp = xpu + (((t4 & 1) * (BAT * 3 * HDIM)) >> 1);
          const float bias = b1[g * HDIM + o];
          float xv[4], hv[4];
#pragma unroll
          for (int r = 0; r < 4; ++r) {
            int b = rbase2 + r;
            xv[r] = ld_bf16(xp, b * 3072 + g * HDIM + o);
            if (g == 0) hv[r] = ld_f32(&h1f[b * HDIM + o]);
          }
          const char* apl = (const char*)h1b + (w * 16 + lr) * 2048 + lk2;
          v4f acc = gemm_sc(apl, bb2, swz2, lk2);
#pragma unroll
          for (int r = 0; r < 4; ++r) {
            int b = rbase2 + r;
            float s = sigm(acc[r] + xv[r] + bias);
            if (g == 0) st_bf16_pair(a5u, b * HDIM + o, f2bf(s * hv[r]), l);
            else        st_f32(&z1[b * HDIM + o], s);
          }
        }
      }
    }
    gbar(bar, 2 * T + 2, wg, t);
  }
}

// ---------------- m97-style 128x128 bf16 GEMM ------------------------------------
// MODE 0: xa0 = gather(emb)[8192,512] x Wx0[3072,512]^T -> bf16 out in (S,3,B,H) layout
// MODE 1: logits = hs1[8192,1024] x Wd[VPAD,1024]^T + bd -> f32 (8192,10000)
template <int MODE>
__global__ void __launch_bounds__(256) k_gemm(
    const u16* __restrict__ A, const u16* __restrict__ Bw,
    const int* __restrict__ gidx, const float* __restrict__ bias,
    void* __restrict__ Out) {
  constexpr int K = MODE ? 1024 : 512;
  constexpr int NB_N = MODE ? (VPAD / 128) : (3072 / 128);

  __shared__ u16 sA[128 * 64];
  __shared__ u16 sB[128 * 64];

  const int nwg = gridDim.x;
  const int cpx = nwg >> 3;
  const int bid = blockIdx.x;
  const int swz = (bid & 7) * cpx + (bid >> 3);
  const int bm = swz / NB_N, bn = swz % NB_N;
  const int m0 = bm * 128, n0 = bn * 128;

  const int t = threadIdx.x;
  const int w = t >> 6, l = t & 63;
  const int lr = l & 15, lk = (l >> 4) * 8;
  const int wm = (w >> 1) * 64, wn = (w & 1) * 64;
  const int kc = (t & 7) * 8;

  int arowg[4];
#pragma unroll
  for (int i = 0; i < 4; ++i) {
    int row = m0 + i * 32 + (t >> 3);
    arowg[i] = (MODE == 0) ? gidx[row] : row;
  }
  int brow[4];
#pragma unroll
  for (int i = 0; i < 4; ++i) brow[i] = n0 + i * 32 + (t >> 3);

  v4f acc[4][4];
#pragma unroll
  for (int mi = 0; mi < 4; ++mi)
#pragma unroll
    for (int ni = 0; ni < 4; ++ni) acc[mi][ni] = v4f{0.f, 0.f, 0.f, 0.f};

  for (int k0 = 0; k0 < K; k0 += 64) {
    __syncthreads();
#pragma unroll
    for (int i = 0; i < 4; ++i) {
      const u16* src = A + (size_t)arowg[i] * K + k0 + kc;
      __builtin_amdgcn_global_load_lds((const __attribute__((address_space(1))) void*)src,
                                       (__attribute__((address_space(3))) void*)(sA + i * 2048 + w * 512),
                                       16, 0, 0);
    }
#pragma unroll
    for (int i = 0; i < 4; ++i) {
      const u16* src = Bw + (size_t)brow[i] * K + k0 + kc;
      __builtin_amdgcn_global_load_lds((const __attribute__((address_space(1))) void*)src,
                                       (__attribute__((address_space(3))) void*)(sB + i * 2048 + w * 512),
                                       16, 0, 0);
    }
    asm volatile("s_waitcnt vmcnt(0)" ::: "memory");
    __syncthreads();
#pragma unroll
    for (int ks = 0; ks < 2; ++ks) {
      v8s af[4], bfr[4];
#pragma unroll
      for (int mi = 0; mi < 4; ++mi) af[mi] = *(const v8s*)&sA[(wm + mi * 16 + lr) * 64 + ks * 32 + lk];
#pragma unroll
      for (int ni = 0; ni < 4; ++ni) bfr[ni] = *(const v8s*)&sB[(wn + ni * 16 + lr) * 64 + ks * 32 + lk];
#pragma unroll
      for (int mi = 0; mi < 4; ++mi)
#pragma unroll
        for (int ni = 0; ni < 4; ++ni)
          acc[mi][ni] = __builtin_amdgcn_mfma_f32_16x16x32_bf16(af[mi], bfr[ni], acc[mi][ni], 0, 0, 0);
    }
  }

#pragma unroll
  for (int mi = 0; mi < 4; ++mi)
#pragma unroll
    for (int ni = 0; ni < 4; ++ni)
#pragma unroll
      for (int r = 0; r < 4; ++r) {
        int grow = m0 + wm + mi * 16 + ((l >> 4) << 2) + r;
        int gcol = n0 + wn + ni * 16 + lr;
        float v = acc[mi][ni][r];
        if (MODE == 0) {
          int s = grow >> 6, b = grow & 63;
          int g = gcol >> 10, o = gcol & 1023;
          ((u16*)Out)[(((size_t)s * 3 + g) * BAT + b) * HDIM + o] = f2bf(v);
        } else {
          if (gcol < VOC) ((float*)Out)[(size_t)grow * VOC + gcol] = v + bias[gcol];
        }
      }
}

// ---------------- small helper kernels --------------------------------------------
__global__ void k_cvt(const float* __restrict__ src, u16* __restrict__ dst, int n, int nsrc) {
  int i = (blockIdx.x * 256 + threadIdx.x) * 4;
  if (i >= n) return;
#pragma unroll
  for (int j = 0; j < 4; ++j) {
    int idx = i + j;
    if (idx < n) dst[idx] = (idx < nsrc) ? f2bf(src[idx]) : (u16)0;
  }
}

__global__ void k_init(const float* __restrict__ hidden,
                       float* h0f, u16* h0b, float* h1f, u16* h1b, int* bar) {
  int i = blockIdx.x * 256 + threadIdx.x;
  if (i < BAT * HDIM) {
    float v0 = hidden[i];
    float v1 = hidden[BAT * HDIM + i];
    h0f[i] = v0; h0b[i] = f2bf(v0);
    h1f[i] = v1; h1b[i] = f2bf(v1);
  }
  if (i < 512) bar[i] = 0;
}

// ---------------- launcher ---------------------------------------------------------
extern "C" void kernel_launch(void* const* d_in, const int* in_sizes, int n_in,
                              void* d_out, int out_size, void* d_ws, size_t ws_size,
                              hipStream_t stream) {
  const int*   inp = (const int*)d_in[0];
  const float* hid = (const float*)d_in[1];
  const float* emb = (const float*)d_in[2];
  const float* Wx0 = (const float*)d_in[3];
  const float* Uh0 = (const float*)d_in[4];
  const float* b0  = (const float*)d_in[5];
  const float* Wx1 = (const float*)d_in[6];
  const float* Uh1 = (const float*)d_in[7];
  const float* b1  = (const float*)d_in[8];
  const float* Wd  = (const float*)d_in[9];
  const float* bd  = (const float*)d_in[10];

  char* ws = (char*)d_ws;
  size_t off = 0;
  auto alloc = [&](size_t bytes) {
    void* p = ws + off;
    off = (off + bytes + 255) & ~(size_t)255;
    return p;
  };
  u16* emb_b = (u16*)alloc(sizeof(u16) * (size_t)VOC * EDIM);
  u16* Wx0_b = (u16*)alloc(sizeof(u16) * 3 * HDIM * EDIM);
  u16* Uh0_b = (u16*)alloc(sizeof(u16) * 3 * HDIM * HDIM);
  u16* Wx1_b = (u16*)alloc(sizeof(u16) * 3 * HDIM * HDIM);
  u16* Uh1_b = (u16*)alloc(sizeof(u16) * 3 * HDIM * HDIM);
  u16* Wd_b  = (u16*)alloc(sizeof(u16) * (size_t)VPAD * HDIM);
  u16* xa0_b = (u16*)alloc(sizeof(u16) * (size_t)SLEN * 3 * BAT * HDIM);
  u16* hs1_b = (u16*)alloc(sizeof(u16) * (size_t)SLEN * BAT * HDIM);
  u16* xp1   = (u16*)alloc(sizeof(u16) * 2 * BAT * 3 * HDIM);
  float* h0f = (float*)alloc(sizeof(float) * BAT * HDIM);
  float* h1f = (float*)alloc(sizeof(float) * BAT * HDIM);
  u16* h0b   = (u16*)alloc(sizeof(u16) * BAT * HDIM);
  u16* h1b   = (u16*)alloc(sizeof(u16) * BAT * HDIM);
  u16* a2    = (u16*)alloc(sizeof(u16) * BAT * HDIM);
  u16* a5    = (u16*)alloc(sizeof(u16) * BAT * HDIM);
  float* z0  = (float*)alloc(sizeof(float) * BAT * HDIM);
  float* z1  = (float*)alloc(sizeof(float) * BAT * HDIM);
  int* bar   = (int*)alloc(sizeof(int) * 512);

  float* logits = (float*)d_out;
  float* outh = logits + (size_t)SLEN * BAT * VOC;

  auto cvt = [&](const float* s, u16* d, int n, int nsrc) {
    k_cvt<<<dim3((n / 4 + 255) / 256), dim3(256), 0, stream>>>(s, d, n, nsrc);
  };
  cvt(emb, emb_b, VOC * EDIM, VOC * EDIM);
  cvt(Wx0, Wx0_b, 3 * HDIM * EDIM, 3 * HDIM * EDIM);
  cvt(Uh0, Uh0_b, 3 * HDIM * HDIM, 3 * HDIM * HDIM);
  cvt(Wx1, Wx1_b, 3 * HDIM * HDIM, 3 * HDIM * HDIM);
  cvt(Uh1, Uh1_b, 3 * HDIM * HDIM, 3 * HDIM * HDIM);
  cvt(Wd, Wd_b, VPAD * HDIM, VOC * HDIM);
  k_init<<<dim3(256), dim3(256), 0, stream>>>(hid, h0f, h0b, h1f, h1b, bar);

  k_gemm<0><<<dim3(64 * 24), dim3(256), 0, stream>>>(emb_b, Wx0_b, inp, (const float*)nullptr, (void*)xa0_b);

  (void)hipFuncSetAttribute(reinterpret_cast<const void*>(k_recur),
                            hipFuncAttributeMaxDynamicSharedMemorySize, 96 * 1024);
  k_recur<<<dim3(NWG_REC), dim3(TPB_REC), 96 * 1024, stream>>>(
      Uh0_b, Wx1_b, Uh1_b, b0, b1, xa0_b,
      h0f, h0b, h1f, h1b, a2, z0, a5, z1, xp1, hs1_b, outh, bar);

  k_gemm<1><<<dim3(64 * 79), dim3(256), 0, stream>>>(hs1_b, Wd_b, (const int*)nullptr, bd, d_out);
}